// Round 7
// baseline (257.448 us; speedup 1.0000x reference)
//
#include <hip/hip_runtime.h>
#include <hip/hip_bf16.h>
#include <hip/hip_fp8.h>

#define NTOK 100000
#define EPS 1e-5f

using frag  = __attribute__((ext_vector_type(8))) short;  // 8 bf16 (4 VGPR)
using f32x4 = __attribute__((ext_vector_type(4))) float;
typedef __hip_bfloat16 bf16;
typedef unsigned short ushort_t;

__device__ inline float bits2f(unsigned int u) { union { unsigned int i; float f; } x; x.i = u; return x.f; }
__device__ inline void bfu_unpack(unsigned int u, float& lo, float& hi) {
  lo = bits2f(u << 16);
  hi = bits2f(u & 0xffff0000u);
}

__device__ inline float4 fp8x4_to_f4(unsigned int u) {
  __hip_fp8_e4m3 a, b, c, d;
  a.__x = u & 0xff; b.__x = (u >> 8) & 0xff; c.__x = (u >> 16) & 0xff; d.__x = (u >> 24) & 0xff;
  return make_float4((float)a, (float)b, (float)c, (float)d);
}
__device__ inline unsigned char f_to_fp8(float f) { __hip_fp8_e4m3 t(f); return t.__x; }

// ---------------------------------------------------------------------------
// fp32 -> bf16 conversions
// ---------------------------------------------------------------------------
__global__ __launch_bounds__(256) void cvt_x_kernel(const float* __restrict__ in,
                                                    bf16* __restrict__ out) {
  const int e = (blockIdx.x * 256 + threadIdx.x) * 4;
  float4 v = *(const float4*)&in[e];
  bf16 o[4] = {__float2bfloat16(v.x), __float2bfloat16(v.y),
               __float2bfloat16(v.z), __float2bfloat16(v.w)};
  *(ulong1*)&out[e] = *(ulong1*)o;
}

__global__ __launch_bounds__(256) void cvt_w_kernel(
    const float* __restrict__ w0, const float* __restrict__ w1,
    const float* __restrict__ w2, const float* __restrict__ w3,
    bf16* __restrict__ out) {
  const int e = (blockIdx.x * 256 + threadIdx.x) * 4;
  const float* src;
  int off;
  if (e < 49152)       { src = w0; off = 0; }
  else if (e < 65536)  { src = w1; off = 49152; }
  else if (e < 131072) { src = w2; off = 65536; }
  else                 { src = w3; off = 131072; }
  float4 v = *(const float4*)&src[e - off];
  bf16 o[4] = {__float2bfloat16(v.x), __float2bfloat16(v.y),
               __float2bfloat16(v.z), __float2bfloat16(v.w)};
  *(ulong1*)&out[e] = *(ulong1*)o;
}

// ---------------------------------------------------------------------------
// Shared GEMM body v2: block = 4 waves x 32 rows = 128-row tile; BOTH A and B
// staged per 128-k step into LDS (32 KB each), cooperatively and coalesced:
// slot g = r*256+tid -> (row = g>>4, u = g&15); LDS slot (row,u) holds global
// 16B-unit (row, u^row&15). 16 threads cover one 256B row -> dense 4KB/round.
// Frag reads: unit (kc*4+kg)^lr at the needed row -> <=2-way bank (verified
// 0 conflicts on the B path in R6; A uses identical algebra).
// KSTEPS>1: next step's A+B prefetched into regs during MFMA (issue-early /
// write-late), single buffer, 2 barriers per step. No early returns (rows
// clamped; stores guarded by caller).
// ---------------------------------------------------------------------------
template<int KSTEPS>
__device__ __forceinline__ void gemm_body(
    const bf16* __restrict__ A,      // activations [M][KTOT]
    const bf16* __restrict__ W,      // weight slab: 128 rows (=cols) x KTOT
    int row0, int M, ushort_t* As, ushort_t* Bs, f32x4 (&acc)[2][8]) {
  const int KTOT = KSTEPS * 128;
  const int tid = threadIdx.x;
  const int lane = tid & 63;
  const int wid = tid >> 6;
  const int lr = lane & 15, kg = lane >> 4;
  const int rb = tid >> 4;        // base row within 16-row stripe (0..15)
  const int uu = tid & 15;        // 16B-unit slot in LDS row
  const int su = uu ^ rb;         // swizzled source unit (row&15 == rb)

  const bf16* agp[8];
  const bf16* bgp[8];
#pragma unroll
  for (int r = 0; r < 8; ++r) {
    int grow = row0 + r * 16 + rb;
    if (grow > M - 1) grow = M - 1;
    agp[r] = A + (size_t)grow * KTOT + su * 8;
    bgp[r] = W + (size_t)(r * 16 + rb) * KTOT + su * 8;
  }
  const int lslot = rb * 128 + uu * 8;  // + r*2048

  uint4 sa[8], sb[8];
#define SLOAD(c)                                                  \
  {                                                               \
    _Pragma("unroll") for (int r = 0; r < 8; ++r) {               \
      sa[r] = *(const uint4*)(agp[r] + (c) * 128);                \
      sb[r] = *(const uint4*)(bgp[r] + (c) * 128);                \
    }                                                             \
  }
#define SWRITE()                                                  \
  {                                                               \
    _Pragma("unroll") for (int r = 0; r < 8; ++r) {               \
      *(uint4*)&As[lslot + r * 2048] = sa[r];                     \
      *(uint4*)&Bs[lslot + r * 2048] = sb[r];                     \
    }                                                             \
  }

  SLOAD(0);
  SWRITE();
  __syncthreads();

#pragma unroll
  for (int c = 0; c < KSTEPS; ++c) {
    if (c + 1 < KSTEPS) SLOAD(c + 1);   // prefetch next step (regs)
#pragma unroll
    for (int kc = 0; kc < 4; ++kc) {
      const int uoff = ((kc * 4 + kg) ^ lr) * 8;
      frag a0 = *(const frag*)&As[(wid * 32 + lr) * 128 + uoff];
      frag a1 = *(const frag*)&As[(wid * 32 + 16 + lr) * 128 + uoff];
#pragma unroll
      for (int j = 0; j < 8; ++j) {
        frag b = *(const frag*)&Bs[(lr + 16 * j) * 128 + uoff];
        acc[0][j] = __builtin_amdgcn_mfma_f32_16x16x32_bf16(a0, b, acc[0][j], 0, 0, 0);
        acc[1][j] = __builtin_amdgcn_mfma_f32_16x16x32_bf16(a1, b, acc[1][j], 0, 0, 0);
      }
    }
    if (c + 1 < KSTEPS) {
      __syncthreads();   // all waves done reading step c
      SWRITE();
      __syncthreads();   // step c+1 visible
    }
  }
#undef SLOAD
#undef SWRITE
}

// ---------------------------------------------------------------------------
// QKV projection (K=128): blockIdx.y 0 -> q (bf16), 1 -> k (fp8), 2 -> v (fp8)
// ---------------------------------------------------------------------------
__global__ __launch_bounds__(256, 2) void k_qkv(
    const bf16* __restrict__ A, const bf16* __restrict__ W,
    const float* __restrict__ bias, bf16* __restrict__ qout,
    unsigned char* __restrict__ kout, unsigned char* __restrict__ vout, int M) {
  __shared__ ushort_t As[16384];
  __shared__ ushort_t Bs[16384];
  const int lane = threadIdx.x & 63;
  const int wid = threadIdx.x >> 6;
  const int row0 = blockIdx.x * 128 + wid * 32;
  const int cbase = blockIdx.y * 128;
  const int lr = lane & 15, kg = lane >> 4;

  f32x4 acc[2][8] = {};
  gemm_body<1>(A, W + (size_t)cbase * 128, blockIdx.x * 128, M, As, Bs, acc);

  float bs[8];
#pragma unroll
  for (int j = 0; j < 8; ++j) bs[j] = bias[cbase + lr + 16 * j];
  const int y = blockIdx.y;
  unsigned char* f8dst = (y == 1) ? kout : vout;
#pragma unroll
  for (int i = 0; i < 2; ++i)
#pragma unroll
    for (int r = 0; r < 4; ++r) {
      const int row = row0 + 16 * i + 4 * kg + r;
      if (row >= M) continue;
      if (y == 0) {
        bf16* orow = qout + (size_t)row * 128 + lr;
#pragma unroll
        for (int j = 0; j < 8; ++j) orow[16 * j] = __float2bfloat16(acc[i][j][r] + bs[j]);
      } else {
        unsigned char* orow = f8dst + (size_t)row * 128 + lr;
#pragma unroll
        for (int j = 0; j < 8; ++j) orow[16 * j] = f_to_fp8(acc[i][j][r] + bs[j]);
      }
    }
}

// ---------------------------------------------------------------------------
// FFN1 (K=128, N=512 via blockIdx.y): bias + relu -> h (bf16)
// ---------------------------------------------------------------------------
__global__ __launch_bounds__(256, 2) void k_ffn1(
    const bf16* __restrict__ A, const bf16* __restrict__ W,
    const float* __restrict__ bias, bf16* __restrict__ out, int M) {
  __shared__ ushort_t As[16384];
  __shared__ ushort_t Bs[16384];
  const int lane = threadIdx.x & 63;
  const int wid = threadIdx.x >> 6;
  const int row0 = blockIdx.x * 128 + wid * 32;
  const int cbase = blockIdx.y * 128;
  const int lr = lane & 15, kg = lane >> 4;

  f32x4 acc[2][8] = {};
  gemm_body<1>(A, W + (size_t)cbase * 128, blockIdx.x * 128, M, As, Bs, acc);

  float bs[8];
#pragma unroll
  for (int j = 0; j < 8; ++j) bs[j] = bias[cbase + lr + 16 * j];
#pragma unroll
  for (int i = 0; i < 2; ++i)
#pragma unroll
    for (int r = 0; r < 4; ++r) {
      const int row = row0 + 16 * i + 4 * kg + r;
      if (row >= M) continue;
      bf16* orow = out + (size_t)row * 512 + cbase + lr;
#pragma unroll
      for (int j = 0; j < 8; ++j)
        orow[16 * j] = __float2bfloat16(fmaxf(acc[i][j][r] + bs[j], 0.f));
    }
}

// ---------------------------------------------------------------------------
// out-proj (K=128) + bias + residual + LN1 -> bf16
// ---------------------------------------------------------------------------
__global__ __launch_bounds__(256, 2) void k_outproj_ln(
    const bf16* __restrict__ A, const bf16* __restrict__ W,
    const float* __restrict__ bias, const bf16* __restrict__ resid,
    const float* __restrict__ g, const float* __restrict__ b,
    bf16* __restrict__ out, int M) {
  __shared__ ushort_t As[16384];
  __shared__ ushort_t Bs[16384];
  const int lane = threadIdx.x & 63;
  const int wid = threadIdx.x >> 6;
  const int row0 = blockIdx.x * 128 + wid * 32;
  const int lr = lane & 15, kg = lane >> 4;

  f32x4 acc[2][8] = {};
  gemm_body<1>(A, W, blockIdx.x * 128, M, As, Bs, acc);

  float bs[8], gs[8], bbs[8];
#pragma unroll
  for (int j = 0; j < 8; ++j) {
    const int c = lr + 16 * j;
    bs[j] = bias[c]; gs[j] = g[c]; bbs[j] = b[c];
  }
#pragma unroll
  for (int i = 0; i < 2; ++i)
#pragma unroll
    for (int r = 0; r < 4; ++r) {
      const int row = row0 + 16 * i + 4 * kg + r;
      const int rr = (row > M - 1) ? (M - 1) : row;
      const bf16* rrow = resid + (size_t)rr * 128 + lr;
      float v[8], psum = 0.f, psq = 0.f;
#pragma unroll
      for (int j = 0; j < 8; ++j) {
        v[j] = acc[i][j][r] + bs[j] + __bfloat162float(rrow[16 * j]);
        psum += v[j];
        psq += v[j] * v[j];
      }
#pragma unroll
      for (int off = 1; off < 16; off <<= 1) {
        psum += __shfl_xor(psum, off);
        psq += __shfl_xor(psq, off);
      }
      const float mean = psum * (1.f / 128.f);
      const float var = psq * (1.f / 128.f) - mean * mean;
      const float rstd = rsqrtf(var + EPS);
      if (row < M) {
        bf16* orow = out + (size_t)row * 128 + lr;
#pragma unroll
        for (int j = 0; j < 8; ++j)
          orow[16 * j] = __float2bfloat16((v[j] - mean) * rstd * gs[j] + bbs[j]);
      }
    }
}

// ---------------------------------------------------------------------------
// FFN2 (K=512, 4 k-steps, A+B prefetched) + bias + residual + LN2 -> fp32
// ---------------------------------------------------------------------------
__global__ __launch_bounds__(256, 2) void k_ffn2_ln(
    const bf16* __restrict__ A,    // h [M][512]
    const bf16* __restrict__ W,    // [128][512]
    const float* __restrict__ bias, const bf16* __restrict__ resid,
    const float* __restrict__ g, const float* __restrict__ b,
    float* __restrict__ out, int M) {
  __shared__ ushort_t As[16384];
  __shared__ ushort_t Bs[16384];
  const int lane = threadIdx.x & 63;
  const int wid = threadIdx.x >> 6;
  const int row0 = blockIdx.x * 128 + wid * 32;
  const int lr = lane & 15, kg = lane >> 4;

  f32x4 acc[2][8] = {};
  gemm_body<4>(A, W, blockIdx.x * 128, M, As, Bs, acc);

  float bs[8], gs[8], bbs[8];
#pragma unroll
  for (int j = 0; j < 8; ++j) {
    const int c = lr + 16 * j;
    bs[j] = bias[c]; gs[j] = g[c]; bbs[j] = b[c];
  }
#pragma unroll
  for (int i = 0; i < 2; ++i)
#pragma unroll
    for (int r = 0; r < 4; ++r) {
      const int row = row0 + 16 * i + 4 * kg + r;
      const int rr = (row > M - 1) ? (M - 1) : row;
      const bf16* rrow = resid + (size_t)rr * 128 + lr;
      float v[8], psum = 0.f, psq = 0.f;
#pragma unroll
      for (int j = 0; j < 8; ++j) {
        v[j] = acc[i][j][r] + bs[j] + __bfloat162float(rrow[16 * j]);
        psum += v[j];
        psq += v[j] * v[j];
      }
#pragma unroll
      for (int off = 1; off < 16; off <<= 1) {
        psum += __shfl_xor(psum, off);
        psq += __shfl_xor(psq, off);
      }
      const float mean = psum * (1.f / 128.f);
      const float var = psq * (1.f / 128.f) - mean * mean;
      const float rstd = rsqrtf(var + EPS);
      if (row < M) {
        float* orow = out + (size_t)row * 128 + lr;
#pragma unroll
        for (int j = 0; j < 8; ++j)
          orow[16 * j] = (v[j] - mean) * rstd * gs[j] + bbs[j];
      }
    }
}

// ---------------------------------------------------------------------------
// Sampled attention, fp8 K/V, 8B gathers (one instruction = 4 sample rows).
// At the L2/L3 service-BW roofline on 410 MB of gathers.
// ---------------------------------------------------------------------------
__global__ __launch_bounds__(256) void attn_kernel(
    const bf16* __restrict__ qb, const unsigned char* __restrict__ kf8,
    const unsigned char* __restrict__ vf8, const int* __restrict__ samples,
    bf16* __restrict__ attn) {
  const int lane = threadIdx.x & 63;
  const int wid = threadIdx.x >> 6;
  const int tok = blockIdx.x * 4 + wid;
  if (tok >= NTOK) return;
  const int qt = lane >> 4;
  const int lr = lane & 15;

  const float scale = 0.17677669529663687f;  // 1/sqrt(32)
  float q8[8];
  {
    uint4 qu = *(const uint4*)&qb[(size_t)tok * 128 + 8 * lr];
    bfu_unpack(qu.x, q8[0], q8[1]);
    bfu_unpack(qu.y, q8[2], q8[3]);
    bfu_unpack(qu.z, q8[4], q8[5]);
    bfu_unpack(qu.w, q8[6], q8[7]);
#pragma unroll
    for (int d = 0; d < 8; ++d) q8[d] *= scale;
  }

  const int myidx = samples[tok * 16 + lr];
  int kidx[4];
#pragma unroll
  for (int jj = 0; jj < 4; ++jj) kidx[jj] = __shfl(myidx, 4 * jj + qt, 16);

  float s[4];
#pragma unroll
  for (int jj = 0; jj < 4; ++jj) {
    uint2 ku = *(const uint2*)&kf8[(size_t)kidx[jj] * 128 + 8 * lr];
    float4 k0 = fp8x4_to_f4(ku.x), k1 = fp8x4_to_f4(ku.y);
    float p = q8[0] * k0.x + q8[1] * k0.y + q8[2] * k0.z + q8[3] * k0.w +
              q8[4] * k1.x + q8[5] * k1.y + q8[6] * k1.z + q8[7] * k1.w;
    p += __shfl_xor(p, 1);
    p += __shfl_xor(p, 2);
    s[jj] = p;
  }

  float m = fmaxf(fmaxf(s[0], s[1]), fmaxf(s[2], s[3]));
  m = fmaxf(m, __shfl_xor(m, 16));
  m = fmaxf(m, __shfl_xor(m, 32));
  float sum = 0.f;
#pragma unroll
  for (int jj = 0; jj < 4; ++jj) {
    s[jj] = __expf(s[jj] - m);
    sum += s[jj];
  }
  sum += __shfl_xor(sum, 16);
  sum += __shfl_xor(sum, 32);
  const float inv = 1.f / sum;

  float a8[8] = {};
#pragma unroll
  for (int jj = 0; jj < 4; ++jj) {
    uint2 vu = *(const uint2*)&vf8[(size_t)kidx[jj] * 128 + 8 * lr];
    float4 v0 = fp8x4_to_f4(vu.x), v1 = fp8x4_to_f4(vu.y);
    const float wj = s[jj] * inv;
    a8[0] += wj * v0.x; a8[1] += wj * v0.y; a8[2] += wj * v0.z; a8[3] += wj * v0.w;
    a8[4] += wj * v1.x; a8[5] += wj * v1.y; a8[6] += wj * v1.z; a8[7] += wj * v1.w;
  }
#pragma unroll
  for (int d = 0; d < 8; ++d) {
    a8[d] += __shfl_xor(a8[d], 16);
    a8[d] += __shfl_xor(a8[d], 32);
  }

  if (qt == 0) {
    uint4 o;
    o.x = (unsigned)__bfloat16_as_ushort(__float2bfloat16(a8[0])) |
          ((unsigned)__bfloat16_as_ushort(__float2bfloat16(a8[1])) << 16);
    o.y = (unsigned)__bfloat16_as_ushort(__float2bfloat16(a8[2])) |
          ((unsigned)__bfloat16_as_ushort(__float2bfloat16(a8[3])) << 16);
    o.z = (unsigned)__bfloat16_as_ushort(__float2bfloat16(a8[4])) |
          ((unsigned)__bfloat16_as_ushort(__float2bfloat16(a8[5])) << 16);
    o.w = (unsigned)__bfloat16_as_ushort(__float2bfloat16(a8[6])) |
          ((unsigned)__bfloat16_as_ushort(__float2bfloat16(a8[7])) << 16);
    *(uint4*)&attn[(size_t)tok * 128 + 8 * lr] = o;
  }
}

extern "C" void kernel_launch(void* const* d_in, const int* in_sizes, int n_in,
                              void* d_out, int out_size, void* d_ws, size_t ws_size,
                              hipStream_t stream) {
  const float* x      = (const float*)d_in[0];
  const int* samples  = (const int*)d_in[1];
  const float* in_w   = (const float*)d_in[2];
  const float* in_b   = (const float*)d_in[3];
  const float* out_w  = (const float*)d_in[4];
  const float* out_b  = (const float*)d_in[5];
  const float* ffn_w1 = (const float*)d_in[6];
  const float* ffn_b1 = (const float*)d_in[7];
  const float* ffn_w2 = (const float*)d_in[8];
  const float* ffn_b2 = (const float*)d_in[9];
  const float* ln1_g  = (const float*)d_in[10];
  const float* ln1_b  = (const float*)d_in[11];
  const float* ln2_g  = (const float*)d_in[12];
  const float* ln2_b  = (const float*)d_in[13];
  float* out = (float*)d_out;

  // ws layout: xb 0 | qb 25.6M | kf8 51.2M | vf8 64M | attn 76.8M | x1b 102.4M | wb 128M
  // h[N][512] aliases [0..102.4M) (xb/qb/kf8/vf8/attn all dead by FFN1)
  char* ws = (char*)d_ws;
  bf16* xb   = (bf16*)(ws);
  bf16* qb   = (bf16*)(ws + 25600000);
  unsigned char* kf8 = (unsigned char*)(ws + 51200000);
  unsigned char* vf8 = (unsigned char*)(ws + 64000000);
  bf16* attn = (bf16*)(ws + 76800000);
  bf16* h    = (bf16*)(ws);
  bf16* x1b  = (bf16*)(ws + 102400000);
  bf16* wb   = (bf16*)(ws + 128000000);
  bf16* in_wb   = wb;
  bf16* out_wb  = wb + 49152;
  bf16* ffn_w1b = wb + 65536;
  bf16* ffn_w2b = wb + 131072;

  const int M = NTOK;
  dim3 blk(256);
  const int gm = (M + 127) / 128;  // 782 blocks (4 waves x 32 rows)

  cvt_x_kernel<<<dim3(12500), blk, 0, stream>>>(x, xb);
  cvt_w_kernel<<<dim3(192), blk, 0, stream>>>(in_w, out_w, ffn_w1, ffn_w2, wb);
  // 1) QKV projection -> qb (bf16), kf8/vf8 (fp8)
  k_qkv<<<dim3(gm, 3), blk, 0, stream>>>(xb, in_wb, in_b, qb, kf8, vf8, M);
  // 2) sampled attention -> attn (bf16)
  attn_kernel<<<dim3((M + 3) / 4), blk, 0, stream>>>(qb, kf8, vf8, samples, attn);
  // 3) out-proj + residual(xb) + LN1 -> x1b
  k_outproj_ln<<<dim3(gm), blk, 0, stream>>>(attn, out_wb, out_b, xb, ln1_g, ln1_b, x1b, M);
  // 4) FFN1 + relu -> h[N][512]
  k_ffn1<<<dim3(gm, 4), blk, 0, stream>>>(x1b, ffn_w1b, ffn_b1, h, M);
  // 5) FFN2 + residual(x1b) + LN2 -> out (fp32)
  k_ffn2_ln<<<dim3(gm), blk, 0, stream>>>(h, ffn_w2b, ffn_b2, x1b, ln2_g, ln2_b, out, M);
}

// Round 8
// 226.273 us; speedup vs baseline: 1.1378x; 1.1378x over previous
//
#include <hip/hip_runtime.h>
#include <hip/hip_bf16.h>
#include <hip/hip_fp8.h>

#define NTOK 100000
#define EPS 1e-5f

using frag  = __attribute__((ext_vector_type(8))) short;  // 8 bf16 (4 VGPR)
using f32x4 = __attribute__((ext_vector_type(4))) float;
typedef __hip_bfloat16 bf16;
typedef unsigned short ushort_t;

__device__ inline float bits2f(unsigned int u) { union { unsigned int i; float f; } x; x.i = u; return x.f; }
__device__ inline void bfu_unpack(unsigned int u, float& lo, float& hi) {
  lo = bits2f(u << 16);
  hi = bits2f(u & 0xffff0000u);
}

__device__ inline float4 fp8x4_to_f4(unsigned int u) {
  __hip_fp8_e4m3 a, b, c, d;
  a.__x = u & 0xff; b.__x = (u >> 8) & 0xff; c.__x = (u >> 16) & 0xff; d.__x = (u >> 24) & 0xff;
  return make_float4((float)a, (float)b, (float)c, (float)d);
}
__device__ inline unsigned char f_to_fp8(float f) { __hip_fp8_e4m3 t(f); return t.__x; }

// ---------------------------------------------------------------------------
// fp32 -> bf16 conversions
// ---------------------------------------------------------------------------
__global__ __launch_bounds__(256) void cvt_x_kernel(const float* __restrict__ in,
                                                    bf16* __restrict__ out) {
  const int e = (blockIdx.x * 256 + threadIdx.x) * 4;
  float4 v = *(const float4*)&in[e];
  bf16 o[4] = {__float2bfloat16(v.x), __float2bfloat16(v.y),
               __float2bfloat16(v.z), __float2bfloat16(v.w)};
  *(ulong1*)&out[e] = *(ulong1*)o;
}

__global__ __launch_bounds__(256) void cvt_w_kernel(
    const float* __restrict__ w0, const float* __restrict__ w1,
    const float* __restrict__ w2, const float* __restrict__ w3,
    bf16* __restrict__ out) {
  const int e = (blockIdx.x * 256 + threadIdx.x) * 4;
  const float* src;
  int off;
  if (e < 49152)       { src = w0; off = 0; }
  else if (e < 65536)  { src = w1; off = 49152; }
  else if (e < 131072) { src = w2; off = 65536; }
  else                 { src = w3; off = 131072; }
  float4 v = *(const float4*)&src[e - off];
  bf16 o[4] = {__float2bfloat16(v.x), __float2bfloat16(v.y),
               __float2bfloat16(v.z), __float2bfloat16(v.w)};
  *(ulong1*)&out[e] = *(ulong1*)o;
}

// ---------------------------------------------------------------------------
// GEMM body (R6-proven): block = 4 waves x 32 rows = 128-row tile. B (128 cols
// x 128 k) staged into a 32 KB LDS slab, XOR-swizzled (LDS unit (row,u) holds
// global unit (row, u^(row&15))); frag reads hit <=2-way banks (measured 0
// conflicts). A-fragments private per wave, straight from HBM. KSTEPS=1 only.
// ---------------------------------------------------------------------------
template<int KSTEPS>
__device__ __forceinline__ void gemm_body(
    const bf16* __restrict__ A,      // activations [M][KTOT]
    const bf16* __restrict__ Wslab,  // W + cbase*KTOT  (rows = this block's cols)
    int row0, int M, ushort_t* Bs, f32x4 (&acc)[2][8]) {
  const int KTOT = KSTEPS * 128;
  const int tid = threadIdx.x;
  const int lane = tid & 63;
  const int lr = lane & 15, kg = lane >> 4;

  int r0 = row0 + lr;      if (r0 > M - 1) r0 = M - 1;
  int r1 = row0 + 16 + lr; if (r1 > M - 1) r1 = M - 1;
  const bf16* a0 = A + (size_t)r0 * KTOT + kg * 8;
  const bf16* a1 = A + (size_t)r1 * KTOT + kg * 8;

  // A frags (HBM; issue first, longest latency)
  frag a[2][4];
#pragma unroll
  for (int kc = 0; kc < 4; ++kc) {
    a[0][kc] = *(const frag*)(a0 + kc * 32);
    a[1][kc] = *(const frag*)(a1 + kc * 32);
  }

  // stage B
  uint4 sreg[8];
#pragma unroll
  for (int r = 0; r < 8; ++r) {
    const int g = r * 256 + tid, row = g >> 4, u = g & 15;
    sreg[r] = *(const uint4*)(Wslab + (size_t)row * KTOT + (u ^ (row & 15)) * 8);
  }
#pragma unroll
  for (int r = 0; r < 8; ++r) {
    const int g = r * 256 + tid, row = g >> 4, u = g & 15;
    *(uint4*)&Bs[row * 128 + u * 8] = sreg[r];
  }
  __syncthreads();

#pragma unroll
  for (int kc = 0; kc < 4; ++kc) {
    const int uoff = ((kc * 4 + kg) ^ lr) * 8;
#pragma unroll
    for (int j = 0; j < 8; ++j) {
      frag b = *(const frag*)&Bs[(lr + 16 * j) * 128 + uoff];
      acc[0][j] = __builtin_amdgcn_mfma_f32_16x16x32_bf16(a[0][kc], b, acc[0][j], 0, 0, 0);
      acc[1][j] = __builtin_amdgcn_mfma_f32_16x16x32_bf16(a[1][kc], b, acc[1][j], 0, 0, 0);
    }
  }
}

// ---------------------------------------------------------------------------
// QKV projection (K=128): blockIdx.y 0 -> q (bf16), 1 -> k (fp8), 2 -> v (fp8)
// ---------------------------------------------------------------------------
__global__ __launch_bounds__(256, 4) void k_qkv(
    const bf16* __restrict__ A, const bf16* __restrict__ W,
    const float* __restrict__ bias, bf16* __restrict__ qout,
    unsigned char* __restrict__ kout, unsigned char* __restrict__ vout, int M) {
  __shared__ ushort_t Bs[16384];
  const int lane = threadIdx.x & 63;
  const int wid = threadIdx.x >> 6;
  const int row0 = blockIdx.x * 128 + wid * 32;
  const int cbase = blockIdx.y * 128;
  const int lr = lane & 15, kg = lane >> 4;

  f32x4 acc[2][8] = {};
  gemm_body<1>(A, W + (size_t)cbase * 128, row0, M, Bs, acc);

  float bs[8];
#pragma unroll
  for (int j = 0; j < 8; ++j) bs[j] = bias[cbase + lr + 16 * j];
  const int y = blockIdx.y;
  unsigned char* f8dst = (y == 1) ? kout : vout;
#pragma unroll
  for (int i = 0; i < 2; ++i)
#pragma unroll
    for (int r = 0; r < 4; ++r) {
      const int row = row0 + 16 * i + 4 * kg + r;
      if (row >= M) continue;
      if (y == 0) {
        bf16* orow = qout + (size_t)row * 128 + lr;
#pragma unroll
        for (int j = 0; j < 8; ++j) orow[16 * j] = __float2bfloat16(acc[i][j][r] + bs[j]);
      } else {
        unsigned char* orow = f8dst + (size_t)row * 128 + lr;
#pragma unroll
        for (int j = 0; j < 8; ++j) orow[16 * j] = f_to_fp8(acc[i][j][r] + bs[j]);
      }
    }
}

// ---------------------------------------------------------------------------
// FFN1 (K=128, N=512 via blockIdx.y): bias + relu -> h (bf16)
// ---------------------------------------------------------------------------
__global__ __launch_bounds__(256, 4) void k_ffn1(
    const bf16* __restrict__ A, const bf16* __restrict__ W,
    const float* __restrict__ bias, bf16* __restrict__ out, int M) {
  __shared__ ushort_t Bs[16384];
  const int lane = threadIdx.x & 63;
  const int wid = threadIdx.x >> 6;
  const int row0 = blockIdx.x * 128 + wid * 32;
  const int cbase = blockIdx.y * 128;
  const int lr = lane & 15, kg = lane >> 4;

  f32x4 acc[2][8] = {};
  gemm_body<1>(A, W + (size_t)cbase * 128, row0, M, Bs, acc);

  float bs[8];
#pragma unroll
  for (int j = 0; j < 8; ++j) bs[j] = bias[cbase + lr + 16 * j];
#pragma unroll
  for (int i = 0; i < 2; ++i)
#pragma unroll
    for (int r = 0; r < 4; ++r) {
      const int row = row0 + 16 * i + 4 * kg + r;
      if (row >= M) continue;
      bf16* orow = out + (size_t)row * 512 + cbase + lr;
#pragma unroll
      for (int j = 0; j < 8; ++j)
        orow[16 * j] = __float2bfloat16(fmaxf(acc[i][j][r] + bs[j], 0.f));
    }
}

// ---------------------------------------------------------------------------
// out-proj (K=128) + bias + residual + LN1 -> bf16
// ---------------------------------------------------------------------------
__global__ __launch_bounds__(256, 4) void k_outproj_ln(
    const bf16* __restrict__ A, const bf16* __restrict__ W,
    const float* __restrict__ bias, const bf16* __restrict__ resid,
    const float* __restrict__ g, const float* __restrict__ b,
    bf16* __restrict__ out, int M) {
  __shared__ ushort_t Bs[16384];
  const int lane = threadIdx.x & 63;
  const int wid = threadIdx.x >> 6;
  const int row0 = blockIdx.x * 128 + wid * 32;
  const int lr = lane & 15, kg = lane >> 4;

  f32x4 acc[2][8] = {};
  gemm_body<1>(A, W, row0, M, Bs, acc);

  float bs[8], gs[8], bbs[8];
#pragma unroll
  for (int j = 0; j < 8; ++j) {
    const int c = lr + 16 * j;
    bs[j] = bias[c]; gs[j] = g[c]; bbs[j] = b[c];
  }
#pragma unroll
  for (int i = 0; i < 2; ++i)
#pragma unroll
    for (int r = 0; r < 4; ++r) {
      const int row = row0 + 16 * i + 4 * kg + r;
      const int rr = (row > M - 1) ? (M - 1) : row;
      const bf16* rrow = resid + (size_t)rr * 128 + lr;
      float v[8], psum = 0.f, psq = 0.f;
#pragma unroll
      for (int j = 0; j < 8; ++j) {
        v[j] = acc[i][j][r] + bs[j] + __bfloat162float(rrow[16 * j]);
        psum += v[j];
        psq += v[j] * v[j];
      }
#pragma unroll
      for (int off = 1; off < 16; off <<= 1) {
        psum += __shfl_xor(psum, off);
        psq += __shfl_xor(psq, off);
      }
      const float mean = psum * (1.f / 128.f);
      const float var = psq * (1.f / 128.f) - mean * mean;
      const float rstd = rsqrtf(var + EPS);
      if (row < M) {
        bf16* orow = out + (size_t)row * 128 + lr;
#pragma unroll
        for (int j = 0; j < 8; ++j)
          orow[16 * j] = __float2bfloat16((v[j] - mean) * rstd * gs[j] + bbs[j]);
      }
    }
}

// ---------------------------------------------------------------------------
// FFN2 (K=512) + bias + residual + LN2 -> fp32 out.
// R6 structure (B per-step in LDS via reg-stage + swizzle) PLUS one-step-ahead
// register prefetch of the A-fragments (ping-pong aC/aN, hand-unrolled so all
// indexing is static -> no scratch). A frags are directly MFMA-consumable
// (lane owns its row, k-contiguous 16B) -- no LDS round trip for A.
// Per step: issue next A (8x16B) + next B (8x16B) loads, then 64 MFMAs on the
// current step; loads retire under the MFMA phase + barriers.
// ---------------------------------------------------------------------------
__global__ __launch_bounds__(256, 3) void k_ffn2_ln(
    const bf16* __restrict__ A,    // h [M][512]
    const bf16* __restrict__ W,    // [128][512]
    const float* __restrict__ bias, const bf16* __restrict__ resid,
    const float* __restrict__ g, const float* __restrict__ b,
    float* __restrict__ out, int M) {
  __shared__ ushort_t Bs[16384];
  const int tid = threadIdx.x;
  const int lane = tid & 63;
  const int wid = tid >> 6;
  const int row0 = blockIdx.x * 128 + wid * 32;
  const int lr = lane & 15, kg = lane >> 4;
  const int rb = tid >> 4;   // staging row within 16-row stripe
  const int uu = tid & 15;   // staging 16B-unit slot
  const int su = uu ^ rb;    // swizzled source unit

  int r0 = row0 + lr;      if (r0 > M - 1) r0 = M - 1;
  int r1 = row0 + 16 + lr; if (r1 > M - 1) r1 = M - 1;
  const bf16* a0 = A + (size_t)r0 * 512 + kg * 8;
  const bf16* a1 = A + (size_t)r1 * 512 + kg * 8;
  const bf16* bgp = W + (size_t)rb * 512 + su * 8;  // + r*16*512 per r
  const int lslot = rb * 128 + uu * 8;              // + r*2048

  f32x4 acc[2][8] = {};
  frag aC0[4], aC1[4], aN0[4], aN1[4];
  uint4 sreg[8];

#define LDA(d0, d1, c)                                            \
  { _Pragma("unroll") for (int kc = 0; kc < 4; ++kc) {            \
      d0[kc] = *(const frag*)(a0 + (c) * 128 + kc * 32);          \
      d1[kc] = *(const frag*)(a1 + (c) * 128 + kc * 32); } }
#define LDB(c)                                                    \
  { _Pragma("unroll") for (int r = 0; r < 8; ++r)                 \
      sreg[r] = *(const uint4*)(bgp + (size_t)r * 16 * 512 + (c) * 128); }
#define WRB()                                                     \
  { _Pragma("unroll") for (int r = 0; r < 8; ++r)                 \
      *(uint4*)&Bs[lslot + r * 2048] = sreg[r]; }
#define STEP(s0, s1)                                              \
  { _Pragma("unroll") for (int kc = 0; kc < 4; ++kc) {            \
      const int uo = ((kc * 4 + kg) ^ lr) * 8;                    \
      _Pragma("unroll") for (int j = 0; j < 8; ++j) {             \
        frag bb = *(const frag*)&Bs[(lr + 16 * j) * 128 + uo];    \
        acc[0][j] = __builtin_amdgcn_mfma_f32_16x16x32_bf16(s0[kc], bb, acc[0][j], 0, 0, 0); \
        acc[1][j] = __builtin_amdgcn_mfma_f32_16x16x32_bf16(s1[kc], bb, acc[1][j], 0, 0, 0); } } }

  LDA(aC0, aC1, 0); LDB(0);
  WRB(); __syncthreads();

  LDA(aN0, aN1, 1); LDB(1);      // prefetch step 1 during step 0 compute
  STEP(aC0, aC1);
  __syncthreads(); WRB(); __syncthreads();

  LDA(aC0, aC1, 2); LDB(2);      // prefetch step 2
  STEP(aN0, aN1);
  __syncthreads(); WRB(); __syncthreads();

  LDA(aN0, aN1, 3); LDB(3);      // prefetch step 3
  STEP(aC0, aC1);
  __syncthreads(); WRB(); __syncthreads();

  STEP(aN0, aN1);
#undef LDA
#undef LDB
#undef WRB
#undef STEP

  float bs[8], gs[8], bbs[8];
#pragma unroll
  for (int j = 0; j < 8; ++j) {
    const int c = lr + 16 * j;
    bs[j] = bias[c]; gs[j] = g[c]; bbs[j] = b[c];
  }
#pragma unroll
  for (int i = 0; i < 2; ++i)
#pragma unroll
    for (int r = 0; r < 4; ++r) {
      const int row = row0 + 16 * i + 4 * kg + r;
      const int rr = (row > M - 1) ? (M - 1) : row;
      const bf16* rrow = resid + (size_t)rr * 128 + lr;
      float v[8], psum = 0.f, psq = 0.f;
#pragma unroll
      for (int j = 0; j < 8; ++j) {
        v[j] = acc[i][j][r] + bs[j] + __bfloat162float(rrow[16 * j]);
        psum += v[j];
        psq += v[j] * v[j];
      }
#pragma unroll
      for (int off = 1; off < 16; off <<= 1) {
        psum += __shfl_xor(psum, off);
        psq += __shfl_xor(psq, off);
      }
      const float mean = psum * (1.f / 128.f);
      const float var = psq * (1.f / 128.f) - mean * mean;
      const float rstd = rsqrtf(var + EPS);
      if (row < M) {
        float* orow = out + (size_t)row * 128 + lr;
#pragma unroll
        for (int j = 0; j < 8; ++j)
          orow[16 * j] = (v[j] - mean) * rstd * gs[j] + bbs[j];
      }
    }
}

// ---------------------------------------------------------------------------
// Sampled attention, fp8 K/V, 8B gathers (one instruction = 4 sample rows).
// At the L2/L3 service-BW roofline on 410 MB of gathers.
// ---------------------------------------------------------------------------
__global__ __launch_bounds__(256) void attn_kernel(
    const bf16* __restrict__ qb, const unsigned char* __restrict__ kf8,
    const unsigned char* __restrict__ vf8, const int* __restrict__ samples,
    bf16* __restrict__ attn) {
  const int lane = threadIdx.x & 63;
  const int wid = threadIdx.x >> 6;
  const int tok = blockIdx.x * 4 + wid;
  if (tok >= NTOK) return;
  const int qt = lane >> 4;
  const int lr = lane & 15;

  const float scale = 0.17677669529663687f;  // 1/sqrt(32)
  float q8[8];
  {
    uint4 qu = *(const uint4*)&qb[(size_t)tok * 128 + 8 * lr];
    bfu_unpack(qu.x, q8[0], q8[1]);
    bfu_unpack(qu.y, q8[2], q8[3]);
    bfu_unpack(qu.z, q8[4], q8[5]);
    bfu_unpack(qu.w, q8[6], q8[7]);
#pragma unroll
    for (int d = 0; d < 8; ++d) q8[d] *= scale;
  }

  const int myidx = samples[tok * 16 + lr];
  int kidx[4];
#pragma unroll
  for (int jj = 0; jj < 4; ++jj) kidx[jj] = __shfl(myidx, 4 * jj + qt, 16);

  float s[4];
#pragma unroll
  for (int jj = 0; jj < 4; ++jj) {
    uint2 ku = *(const uint2*)&kf8[(size_t)kidx[jj] * 128 + 8 * lr];
    float4 k0 = fp8x4_to_f4(ku.x), k1 = fp8x4_to_f4(ku.y);
    float p = q8[0] * k0.x + q8[1] * k0.y + q8[2] * k0.z + q8[3] * k0.w +
              q8[4] * k1.x + q8[5] * k1.y + q8[6] * k1.z + q8[7] * k1.w;
    p += __shfl_xor(p, 1);
    p += __shfl_xor(p, 2);
    s[jj] = p;
  }

  float m = fmaxf(fmaxf(s[0], s[1]), fmaxf(s[2], s[3]));
  m = fmaxf(m, __shfl_xor(m, 16));
  m = fmaxf(m, __shfl_xor(m, 32));
  float sum = 0.f;
#pragma unroll
  for (int jj = 0; jj < 4; ++jj) {
    s[jj] = __expf(s[jj] - m);
    sum += s[jj];
  }
  sum += __shfl_xor(sum, 16);
  sum += __shfl_xor(sum, 32);
  const float inv = 1.f / sum;

  float a8[8] = {};
#pragma unroll
  for (int jj = 0; jj < 4; ++jj) {
    uint2 vu = *(const uint2*)&vf8[(size_t)kidx[jj] * 128 + 8 * lr];
    float4 v0 = fp8x4_to_f4(vu.x), v1 = fp8x4_to_f4(vu.y);
    const float wj = s[jj] * inv;
    a8[0] += wj * v0.x; a8[1] += wj * v0.y; a8[2] += wj * v0.z; a8[3] += wj * v0.w;
    a8[4] += wj * v1.x; a8[5] += wj * v1.y; a8[6] += wj * v1.z; a8[7] += wj * v1.w;
  }
#pragma unroll
  for (int d = 0; d < 8; ++d) {
    a8[d] += __shfl_xor(a8[d], 16);
    a8[d] += __shfl_xor(a8[d], 32);
  }

  if (qt == 0) {
    uint4 o;
    o.x = (unsigned)__bfloat16_as_ushort(__float2bfloat16(a8[0])) |
          ((unsigned)__bfloat16_as_ushort(__float2bfloat16(a8[1])) << 16);
    o.y = (unsigned)__bfloat16_as_ushort(__float2bfloat16(a8[2])) |
          ((unsigned)__bfloat16_as_ushort(__float2bfloat16(a8[3])) << 16);
    o.z = (unsigned)__bfloat16_as_ushort(__float2bfloat16(a8[4])) |
          ((unsigned)__bfloat16_as_ushort(__float2bfloat16(a8[5])) << 16);
    o.w = (unsigned)__bfloat16_as_ushort(__float2bfloat16(a8[6])) |
          ((unsigned)__bfloat16_as_ushort(__float2bfloat16(a8[7])) << 16);
    *(uint4*)&attn[(size_t)tok * 128 + 8 * lr] = o;
  }
}

extern "C" void kernel_launch(void* const* d_in, const int* in_sizes, int n_in,
                              void* d_out, int out_size, void* d_ws, size_t ws_size,
                              hipStream_t stream) {
  const float* x      = (const float*)d_in[0];
  const int* samples  = (const int*)d_in[1];
  const float* in_w   = (const float*)d_in[2];
  const float* in_b   = (const float*)d_in[3];
  const float* out_w  = (const float*)d_in[4];
  const float* out_b  = (const float*)d_in[5];
  const float* ffn_w1 = (const float*)d_in[6];
  const float* ffn_b1 = (const float*)d_in[7];
  const float* ffn_w2 = (const float*)d_in[8];
  const float* ffn_b2 = (const float*)d_in[9];
  const float* ln1_g  = (const float*)d_in[10];
  const float* ln1_b  = (const float*)d_in[11];
  const float* ln2_g  = (const float*)d_in[12];
  const float* ln2_b  = (const float*)d_in[13];
  float* out = (float*)d_out;

  // ws layout: xb 0 | qb 25.6M | kf8 51.2M | vf8 64M | attn 76.8M | x1b 102.4M | wb 128M
  // h[N][512] aliases [0..102.4M) (xb/qb/kf8/vf8/attn all dead by FFN1)
  char* ws = (char*)d_ws;
  bf16* xb   = (bf16*)(ws);
  bf16* qb   = (bf16*)(ws + 25600000);
  unsigned char* kf8 = (unsigned char*)(ws + 51200000);
  unsigned char* vf8 = (unsigned char*)(ws + 64000000);
  bf16* attn = (bf16*)(ws + 76800000);
  bf16* h    = (bf16*)(ws);
  bf16* x1b  = (bf16*)(ws + 102400000);
  bf16* wb   = (bf16*)(ws + 128000000);
  bf16* in_wb   = wb;
  bf16* out_wb  = wb + 49152;
  bf16* ffn_w1b = wb + 65536;
  bf16* ffn_w2b = wb + 131072;

  const int M = NTOK;
  dim3 blk(256);
  const int gm = (M + 127) / 128;  // 782 blocks (4 waves x 32 rows)

  cvt_x_kernel<<<dim3(12500), blk, 0, stream>>>(x, xb);
  cvt_w_kernel<<<dim3(192), blk, 0, stream>>>(in_w, out_w, ffn_w1, ffn_w2, wb);
  // 1) QKV projection -> qb (bf16), kf8/vf8 (fp8)
  k_qkv<<<dim3(gm, 3), blk, 0, stream>>>(xb, in_wb, in_b, qb, kf8, vf8, M);
  // 2) sampled attention -> attn (bf16)
  attn_kernel<<<dim3((M + 3) / 4), blk, 0, stream>>>(qb, kf8, vf8, samples, attn);
  // 3) out-proj + residual(xb) + LN1 -> x1b
  k_outproj_ln<<<dim3(gm), blk, 0, stream>>>(attn, out_wb, out_b, xb, ln1_g, ln1_b, x1b, M);
  // 4) FFN1 + relu -> h[N][512]
  k_ffn1<<<dim3(gm, 4), blk, 0, stream>>>(x1b, ffn_w1b, ffn_b1, h, M);
  // 5) FFN2 + residual(x1b) + LN2 -> out (fp32)
  k_ffn2_ln<<<dim3(gm), blk, 0, stream>>>(h, ffn_w2b, ffn_b2, x1b, ln2_g, ln2_b, out, M);
}

// Round 9
// 196.943 us; speedup vs baseline: 1.3072x; 1.1489x over previous
//
#include <hip/hip_runtime.h>
#include <hip/hip_bf16.h>
#include <hip/hip_fp8.h>

#define NTOK 100000
#define EPS 1e-5f

using frag  = __attribute__((ext_vector_type(8))) short;  // 8 bf16 (4 VGPR)
using f32x4 = __attribute__((ext_vector_type(4))) float;
typedef __hip_bfloat16 bf16;
typedef unsigned short ushort_t;

__device__ inline float bits2f(unsigned int u) { union { unsigned int i; float f; } x; x.i = u; return x.f; }
__device__ inline void bfu_unpack(unsigned int u, float& lo, float& hi) {
  lo = bits2f(u << 16);
  hi = bits2f(u & 0xffff0000u);
}

__device__ inline float4 fp8x4_to_f4(unsigned int u) {
  __hip_fp8_e4m3 a, b, c, d;
  a.__x = u & 0xff; b.__x = (u >> 8) & 0xff; c.__x = (u >> 16) & 0xff; d.__x = (u >> 24) & 0xff;
  return make_float4((float)a, (float)b, (float)c, (float)d);
}
__device__ inline unsigned char f_to_fp8(float f) { __hip_fp8_e4m3 t(f); return t.__x; }

// async global->LDS, 16B per lane; zero VGPR staging cost.
#define GL_LDS16(gsrc, ldst)                                                  \
  __builtin_amdgcn_global_load_lds(                                           \
      (const __attribute__((address_space(1))) void*)(gsrc),                  \
      (__attribute__((address_space(3))) void*)(ldst), 16, 0, 0)

// ---------------------------------------------------------------------------
// fp32 -> bf16 conversions
// ---------------------------------------------------------------------------
__global__ __launch_bounds__(256) void cvt_x_kernel(const float* __restrict__ in,
                                                    bf16* __restrict__ out) {
  const int e = (blockIdx.x * 256 + threadIdx.x) * 4;
  float4 v = *(const float4*)&in[e];
  bf16 o[4] = {__float2bfloat16(v.x), __float2bfloat16(v.y),
               __float2bfloat16(v.z), __float2bfloat16(v.w)};
  *(ulong1*)&out[e] = *(ulong1*)o;
}

__global__ __launch_bounds__(256) void cvt_w_kernel(
    const float* __restrict__ w0, const float* __restrict__ w1,
    const float* __restrict__ w2, const float* __restrict__ w3,
    bf16* __restrict__ out) {
  const int e = (blockIdx.x * 256 + threadIdx.x) * 4;
  const float* src;
  int off;
  if (e < 49152)       { src = w0; off = 0; }
  else if (e < 65536)  { src = w1; off = 49152; }
  else if (e < 131072) { src = w2; off = 65536; }
  else                 { src = w3; off = 131072; }
  float4 v = *(const float4*)&src[e - off];
  bf16 o[4] = {__float2bfloat16(v.x), __float2bfloat16(v.y),
               __float2bfloat16(v.z), __float2bfloat16(v.w)};
  *(ulong1*)&out[e] = *(ulong1*)o;
}

// ---------------------------------------------------------------------------
// B staging via global_load_lds: LDS slot g = r*256+tid (row=g>>4, u=g&15) at
// byte offset g*16 -- LINEAR in lane (wave base + lane*16, the HW pattern).
// Swizzle lives in the per-lane GLOBAL address: unit u^(row&15) of row.
// MFMA frag read (unchanged, measured 0 conflicts): unit (kc*4+kg)^lr.
// ---------------------------------------------------------------------------
__device__ __forceinline__ void stage_B(const bf16* __restrict__ Wslab, int KTOT,
                                        int c, ushort_t* Bs, int tid) {
#pragma unroll
  for (int r = 0; r < 8; ++r) {
    const int g = r * 256 + tid, row = g >> 4, u = g & 15;
    GL_LDS16(Wslab + (size_t)row * KTOT + (size_t)c * 128 + (u ^ (row & 15)) * 8,
             Bs + g * 8);
  }
}

// ---------------------------------------------------------------------------
// K=128 GEMM body: block = 4 waves x 32 rows. A-frags private (HBM, issued
// first); B staged via stage_B. One barrier.
// ---------------------------------------------------------------------------
__device__ __forceinline__ void gemm_body128(
    const bf16* __restrict__ A, const bf16* __restrict__ Wslab,
    int row0, int M, ushort_t* Bs, f32x4 (&acc)[2][8]) {
  const int tid = threadIdx.x;
  const int lane = tid & 63;
  const int lr = lane & 15, kg = lane >> 4;

  int r0 = row0 + lr;      if (r0 > M - 1) r0 = M - 1;
  int r1 = row0 + 16 + lr; if (r1 > M - 1) r1 = M - 1;
  const bf16* a0 = A + (size_t)r0 * 128 + kg * 8;
  const bf16* a1 = A + (size_t)r1 * 128 + kg * 8;

  frag a[2][4];
#pragma unroll
  for (int kc = 0; kc < 4; ++kc) {
    a[0][kc] = *(const frag*)(a0 + kc * 32);
    a[1][kc] = *(const frag*)(a1 + kc * 32);
  }
  stage_B(Wslab, 128, 0, Bs, tid);
  __syncthreads();  // drains vmcnt(0): B in LDS, A in regs

#pragma unroll
  for (int kc = 0; kc < 4; ++kc) {
    const int uoff = ((kc * 4 + kg) ^ lr) * 8;
#pragma unroll
    for (int j = 0; j < 8; ++j) {
      frag b = *(const frag*)&Bs[(lr + 16 * j) * 128 + uoff];
      acc[0][j] = __builtin_amdgcn_mfma_f32_16x16x32_bf16(a[0][kc], b, acc[0][j], 0, 0, 0);
      acc[1][j] = __builtin_amdgcn_mfma_f32_16x16x32_bf16(a[1][kc], b, acc[1][j], 0, 0, 0);
    }
  }
}

// ---------------------------------------------------------------------------
// QKV projection (K=128): blockIdx.y 0 -> q (bf16), 1 -> k (fp8), 2 -> v (fp8)
// ---------------------------------------------------------------------------
__global__ __launch_bounds__(256, 4) void k_qkv(
    const bf16* __restrict__ A, const bf16* __restrict__ W,
    const float* __restrict__ bias, bf16* __restrict__ qout,
    unsigned char* __restrict__ kout, unsigned char* __restrict__ vout, int M) {
  __shared__ ushort_t Bs[16384];
  const int lane = threadIdx.x & 63;
  const int wid = threadIdx.x >> 6;
  const int row0 = blockIdx.x * 128 + wid * 32;
  const int cbase = blockIdx.y * 128;
  const int lr = lane & 15, kg = lane >> 4;

  f32x4 acc[2][8] = {};
  gemm_body128(A, W + (size_t)cbase * 128, row0, M, Bs, acc);

  float bs[8];
#pragma unroll
  for (int j = 0; j < 8; ++j) bs[j] = bias[cbase + lr + 16 * j];
  const int y = blockIdx.y;
  unsigned char* f8dst = (y == 1) ? kout : vout;
#pragma unroll
  for (int i = 0; i < 2; ++i)
#pragma unroll
    for (int r = 0; r < 4; ++r) {
      const int row = row0 + 16 * i + 4 * kg + r;
      if (row >= M) continue;
      if (y == 0) {
        bf16* orow = qout + (size_t)row * 128 + lr;
#pragma unroll
        for (int j = 0; j < 8; ++j) orow[16 * j] = __float2bfloat16(acc[i][j][r] + bs[j]);
      } else {
        unsigned char* orow = f8dst + (size_t)row * 128 + lr;
#pragma unroll
        for (int j = 0; j < 8; ++j) orow[16 * j] = f_to_fp8(acc[i][j][r] + bs[j]);
      }
    }
}

// ---------------------------------------------------------------------------
// FFN1 (K=128, N=512 via blockIdx.y): bias + relu -> h (bf16)
// ---------------------------------------------------------------------------
__global__ __launch_bounds__(256, 4) void k_ffn1(
    const bf16* __restrict__ A, const bf16* __restrict__ W,
    const float* __restrict__ bias, bf16* __restrict__ out, int M) {
  __shared__ ushort_t Bs[16384];
  const int lane = threadIdx.x & 63;
  const int wid = threadIdx.x >> 6;
  const int row0 = blockIdx.x * 128 + wid * 32;
  const int cbase = blockIdx.y * 128;
  const int lr = lane & 15, kg = lane >> 4;

  f32x4 acc[2][8] = {};
  gemm_body128(A, W + (size_t)cbase * 128, row0, M, Bs, acc);

  float bs[8];
#pragma unroll
  for (int j = 0; j < 8; ++j) bs[j] = bias[cbase + lr + 16 * j];
#pragma unroll
  for (int i = 0; i < 2; ++i)
#pragma unroll
    for (int r = 0; r < 4; ++r) {
      const int row = row0 + 16 * i + 4 * kg + r;
      if (row >= M) continue;
      bf16* orow = out + (size_t)row * 512 + cbase + lr;
#pragma unroll
      for (int j = 0; j < 8; ++j)
        orow[16 * j] = __float2bfloat16(fmaxf(acc[i][j][r] + bs[j], 0.f));
    }
}

// ---------------------------------------------------------------------------
// out-proj (K=128) + bias + residual + LN1 -> bf16
// ---------------------------------------------------------------------------
__global__ __launch_bounds__(256, 4) void k_outproj_ln(
    const bf16* __restrict__ A, const bf16* __restrict__ W,
    const float* __restrict__ bias, const bf16* __restrict__ resid,
    const float* __restrict__ g, const float* __restrict__ b,
    bf16* __restrict__ out, int M) {
  __shared__ ushort_t Bs[16384];
  const int lane = threadIdx.x & 63;
  const int wid = threadIdx.x >> 6;
  const int row0 = blockIdx.x * 128 + wid * 32;
  const int lr = lane & 15, kg = lane >> 4;

  f32x4 acc[2][8] = {};
  gemm_body128(A, W, row0, M, Bs, acc);

  float bs[8], gs[8], bbs[8];
#pragma unroll
  for (int j = 0; j < 8; ++j) {
    const int c = lr + 16 * j;
    bs[j] = bias[c]; gs[j] = g[c]; bbs[j] = b[c];
  }
#pragma unroll
  for (int i = 0; i < 2; ++i)
#pragma unroll
    for (int r = 0; r < 4; ++r) {
      const int row = row0 + 16 * i + 4 * kg + r;
      const int rr = (row > M - 1) ? (M - 1) : row;
      const bf16* rrow = resid + (size_t)rr * 128 + lr;
      float v[8], psum = 0.f, psq = 0.f;
#pragma unroll
      for (int j = 0; j < 8; ++j) {
        v[j] = acc[i][j][r] + bs[j] + __bfloat162float(rrow[16 * j]);
        psum += v[j];
        psq += v[j] * v[j];
      }
#pragma unroll
      for (int off = 1; off < 16; off <<= 1) {
        psum += __shfl_xor(psum, off);
        psq += __shfl_xor(psq, off);
      }
      const float mean = psum * (1.f / 128.f);
      const float var = psq * (1.f / 128.f) - mean * mean;
      const float rstd = rsqrtf(var + EPS);
      if (row < M) {
        bf16* orow = out + (size_t)row * 128 + lr;
#pragma unroll
        for (int j = 0; j < 8; ++j)
          orow[16 * j] = __float2bfloat16((v[j] - mean) * rstd * gs[j] + bbs[j]);
      }
    }
}

// ---------------------------------------------------------------------------
// FFN2 (K=512, 4 k-steps) + bias + residual + LN2 -> fp32 out.
// Double-buffered 2x32KB LDS for B via global_load_lds (zero-VGPR staging);
// A ping-pong in registers (static indexing). One barrier per step; next
// step's A+B issued before the current step's MFMAs so their latency hides
// under compute + the barrier's vmcnt drain. No register spill (~115 VGPR).
// ---------------------------------------------------------------------------
__global__ __launch_bounds__(256, 2) void k_ffn2_ln(
    const bf16* __restrict__ A,    // h [M][512]
    const bf16* __restrict__ W,    // [128][512]
    const float* __restrict__ bias, const bf16* __restrict__ resid,
    const float* __restrict__ g, const float* __restrict__ b,
    float* __restrict__ out, int M) {
  __shared__ ushort_t Bs0[16384];
  __shared__ ushort_t Bs1[16384];
  const int tid = threadIdx.x;
  const int lane = tid & 63;
  const int wid = tid >> 6;
  const int row0 = blockIdx.x * 128 + wid * 32;
  const int lr = lane & 15, kg = lane >> 4;

  int r0 = row0 + lr;      if (r0 > M - 1) r0 = M - 1;
  int r1 = row0 + 16 + lr; if (r1 > M - 1) r1 = M - 1;
  const bf16* a0 = A + (size_t)r0 * 512 + kg * 8;
  const bf16* a1 = A + (size_t)r1 * 512 + kg * 8;

  f32x4 acc[2][8] = {};
  frag aC0[4], aC1[4], aN0[4], aN1[4];

#define LDA(d0, d1, c)                                            \
  { _Pragma("unroll") for (int kc = 0; kc < 4; ++kc) {            \
      d0[kc] = *(const frag*)(a0 + (c) * 128 + kc * 32);          \
      d1[kc] = *(const frag*)(a1 + (c) * 128 + kc * 32); } }
#define STEP(B, s0, s1)                                           \
  { _Pragma("unroll") for (int kc = 0; kc < 4; ++kc) {            \
      const int uo = ((kc * 4 + kg) ^ lr) * 8;                    \
      _Pragma("unroll") for (int j = 0; j < 8; ++j) {             \
        frag bb = *(const frag*)&B[(lr + 16 * j) * 128 + uo];     \
        acc[0][j] = __builtin_amdgcn_mfma_f32_16x16x32_bf16(s0[kc], bb, acc[0][j], 0, 0, 0); \
        acc[1][j] = __builtin_amdgcn_mfma_f32_16x16x32_bf16(s1[kc], bb, acc[1][j], 0, 0, 0); } } }

  LDA(aC0, aC1, 0);
  stage_B(W, 512, 0, Bs0, tid);
  __syncthreads();                       // vmcnt(0): Bs0 + aC ready

  LDA(aN0, aN1, 1);                      // prefetch step 1
  stage_B(W, 512, 1, Bs1, tid);
  STEP(Bs0, aC0, aC1);
  __syncthreads();                       // Bs1 + aN ready; Bs0 free

  LDA(aC0, aC1, 2);                      // prefetch step 2
  stage_B(W, 512, 2, Bs0, tid);
  STEP(Bs1, aN0, aN1);
  __syncthreads();

  LDA(aN0, aN1, 3);                      // prefetch step 3
  stage_B(W, 512, 3, Bs1, tid);
  STEP(Bs0, aC0, aC1);
  __syncthreads();

  STEP(Bs1, aN0, aN1);
#undef LDA
#undef STEP

  float bs[8], gs[8], bbs[8];
#pragma unroll
  for (int j = 0; j < 8; ++j) {
    const int c = lr + 16 * j;
    bs[j] = bias[c]; gs[j] = g[c]; bbs[j] = b[c];
  }
#pragma unroll
  for (int i = 0; i < 2; ++i)
#pragma unroll
    for (int r = 0; r < 4; ++r) {
      const int row = row0 + 16 * i + 4 * kg + r;
      const int rr = (row > M - 1) ? (M - 1) : row;
      const bf16* rrow = resid + (size_t)rr * 128 + lr;
      float v[8], psum = 0.f, psq = 0.f;
#pragma unroll
      for (int j = 0; j < 8; ++j) {
        v[j] = acc[i][j][r] + bs[j] + __bfloat162float(rrow[16 * j]);
        psum += v[j];
        psq += v[j] * v[j];
      }
#pragma unroll
      for (int off = 1; off < 16; off <<= 1) {
        psum += __shfl_xor(psum, off);
        psq += __shfl_xor(psq, off);
      }
      const float mean = psum * (1.f / 128.f);
      const float var = psq * (1.f / 128.f) - mean * mean;
      const float rstd = rsqrtf(var + EPS);
      if (row < M) {
        float* orow = out + (size_t)row * 128 + lr;
#pragma unroll
        for (int j = 0; j < 8; ++j)
          orow[16 * j] = (v[j] - mean) * rstd * gs[j] + bbs[j];
      }
    }
}

// ---------------------------------------------------------------------------
// Sampled attention, fp8 K/V, 8B gathers (one instruction = 4 sample rows).
// At the L2/L3 service-BW roofline on 410 MB of gathers.
// ---------------------------------------------------------------------------
__global__ __launch_bounds__(256) void attn_kernel(
    const bf16* __restrict__ qb, const unsigned char* __restrict__ kf8,
    const unsigned char* __restrict__ vf8, const int* __restrict__ samples,
    bf16* __restrict__ attn) {
  const int lane = threadIdx.x & 63;
  const int wid = threadIdx.x >> 6;
  const int tok = blockIdx.x * 4 + wid;
  if (tok >= NTOK) return;
  const int qt = lane >> 4;
  const int lr = lane & 15;

  const float scale = 0.17677669529663687f;  // 1/sqrt(32)
  float q8[8];
  {
    uint4 qu = *(const uint4*)&qb[(size_t)tok * 128 + 8 * lr];
    bfu_unpack(qu.x, q8[0], q8[1]);
    bfu_unpack(qu.y, q8[2], q8[3]);
    bfu_unpack(qu.z, q8[4], q8[5]);
    bfu_unpack(qu.w, q8[6], q8[7]);
#pragma unroll
    for (int d = 0; d < 8; ++d) q8[d] *= scale;
  }

  const int myidx = samples[tok * 16 + lr];
  int kidx[4];
#pragma unroll
  for (int jj = 0; jj < 4; ++jj) kidx[jj] = __shfl(myidx, 4 * jj + qt, 16);

  float s[4];
#pragma unroll
  for (int jj = 0; jj < 4; ++jj) {
    uint2 ku = *(const uint2*)&kf8[(size_t)kidx[jj] * 128 + 8 * lr];
    float4 k0 = fp8x4_to_f4(ku.x), k1 = fp8x4_to_f4(ku.y);
    float p = q8[0] * k0.x + q8[1] * k0.y + q8[2] * k0.z + q8[3] * k0.w +
              q8[4] * k1.x + q8[5] * k1.y + q8[6] * k1.z + q8[7] * k1.w;
    p += __shfl_xor(p, 1);
    p += __shfl_xor(p, 2);
    s[jj] = p;
  }

  float m = fmaxf(fmaxf(s[0], s[1]), fmaxf(s[2], s[3]));
  m = fmaxf(m, __shfl_xor(m, 16));
  m = fmaxf(m, __shfl_xor(m, 32));
  float sum = 0.f;
#pragma unroll
  for (int jj = 0; jj < 4; ++jj) {
    s[jj] = __expf(s[jj] - m);
    sum += s[jj];
  }
  sum += __shfl_xor(sum, 16);
  sum += __shfl_xor(sum, 32);
  const float inv = 1.f / sum;

  float a8[8] = {};
#pragma unroll
  for (int jj = 0; jj < 4; ++jj) {
    uint2 vu = *(const uint2*)&vf8[(size_t)kidx[jj] * 128 + 8 * lr];
    float4 v0 = fp8x4_to_f4(vu.x), v1 = fp8x4_to_f4(vu.y);
    const float wj = s[jj] * inv;
    a8[0] += wj * v0.x; a8[1] += wj * v0.y; a8[2] += wj * v0.z; a8[3] += wj * v0.w;
    a8[4] += wj * v1.x; a8[5] += wj * v1.y; a8[6] += wj * v1.z; a8[7] += wj * v1.w;
  }
#pragma unroll
  for (int d = 0; d < 8; ++d) {
    a8[d] += __shfl_xor(a8[d], 16);
    a8[d] += __shfl_xor(a8[d], 32);
  }

  if (qt == 0) {
    uint4 o;
    o.x = (unsigned)__bfloat16_as_ushort(__float2bfloat16(a8[0])) |
          ((unsigned)__bfloat16_as_ushort(__float2bfloat16(a8[1])) << 16);
    o.y = (unsigned)__bfloat16_as_ushort(__float2bfloat16(a8[2])) |
          ((unsigned)__bfloat16_as_ushort(__float2bfloat16(a8[3])) << 16);
    o.z = (unsigned)__bfloat16_as_ushort(__float2bfloat16(a8[4])) |
          ((unsigned)__bfloat16_as_ushort(__float2bfloat16(a8[5])) << 16);
    o.w = (unsigned)__bfloat16_as_ushort(__float2bfloat16(a8[6])) |
          ((unsigned)__bfloat16_as_ushort(__float2bfloat16(a8[7])) << 16);
    *(uint4*)&attn[(size_t)tok * 128 + 8 * lr] = o;
  }
}

extern "C" void kernel_launch(void* const* d_in, const int* in_sizes, int n_in,
                              void* d_out, int out_size, void* d_ws, size_t ws_size,
                              hipStream_t stream) {
  const float* x      = (const float*)d_in[0];
  const int* samples  = (const int*)d_in[1];
  const float* in_w   = (const float*)d_in[2];
  const float* in_b   = (const float*)d_in[3];
  const float* out_w  = (const float*)d_in[4];
  const float* out_b  = (const float*)d_in[5];
  const float* ffn_w1 = (const float*)d_in[6];
  const float* ffn_b1 = (const float*)d_in[7];
  const float* ffn_w2 = (const float*)d_in[8];
  const float* ffn_b2 = (const float*)d_in[9];
  const float* ln1_g  = (const float*)d_in[10];
  const float* ln1_b  = (const float*)d_in[11];
  const float* ln2_g  = (const float*)d_in[12];
  const float* ln2_b  = (const float*)d_in[13];
  float* out = (float*)d_out;

  // ws layout: xb 0 | qb 25.6M | kf8 51.2M | vf8 64M | attn 76.8M | x1b 102.4M | wb 128M
  // h[N][512] aliases [0..102.4M) (xb/qb/kf8/vf8/attn all dead by FFN1)
  char* ws = (char*)d_ws;
  bf16* xb   = (bf16*)(ws);
  bf16* qb   = (bf16*)(ws + 25600000);
  unsigned char* kf8 = (unsigned char*)(ws + 51200000);
  unsigned char* vf8 = (unsigned char*)(ws + 64000000);
  bf16* attn = (bf16*)(ws + 76800000);
  bf16* h    = (bf16*)(ws);
  bf16* x1b  = (bf16*)(ws + 102400000);
  bf16* wb   = (bf16*)(ws + 128000000);
  bf16* in_wb   = wb;
  bf16* out_wb  = wb + 49152;
  bf16* ffn_w1b = wb + 65536;
  bf16* ffn_w2b = wb + 131072;

  const int M = NTOK;
  dim3 blk(256);
  const int gm = (M + 127) / 128;  // 782 blocks (4 waves x 32 rows)

  cvt_x_kernel<<<dim3(12500), blk, 0, stream>>>(x, xb);
  cvt_w_kernel<<<dim3(192), blk, 0, stream>>>(in_w, out_w, ffn_w1, ffn_w2, wb);
  // 1) QKV projection -> qb (bf16), kf8/vf8 (fp8)
  k_qkv<<<dim3(gm, 3), blk, 0, stream>>>(xb, in_wb, in_b, qb, kf8, vf8, M);
  // 2) sampled attention -> attn (bf16)
  attn_kernel<<<dim3((M + 3) / 4), blk, 0, stream>>>(qb, kf8, vf8, samples, attn);
  // 3) out-proj + residual(xb) + LN1 -> x1b
  k_outproj_ln<<<dim3(gm), blk, 0, stream>>>(attn, out_wb, out_b, xb, ln1_g, ln1_b, x1b, M);
  // 4) FFN1 + relu -> h[N][512]
  k_ffn1<<<dim3(gm, 4), blk, 0, stream>>>(x1b, ffn_w1b, ffn_b1, h, M);
  // 5) FFN2 + residual(x1b) + LN2 -> out (fp32)
  k_ffn2_ln<<<dim3(gm), blk, 0, stream>>>(h, ffn_w2b, ffn_b2, x1b, ln2_g, ln2_b, out, M);
}